// Round 5
// baseline (192.437 us; speedup 1.0000x reference)
//
#include <hip/hip_runtime.h>
#include <hip/hip_bf16.h>

typedef __attribute__((ext_vector_type(8))) short bf16x8;
typedef __attribute__((ext_vector_type(4))) float f32x4;

constexpr int NB = 16, CIN = 256, COUT = 256, TDIM = 4096, KS = 3, PADV = 1;
constexpr int TT = 128;            // t per block
constexpr int BK = 64;             // K-step (kc = k*CIN + c)
constexpr int KTOT = KS * CIN;     // 768
constexpr int NSTEP = KTOT / BK;   // 12

typedef __attribute__((address_space(1))) const unsigned int gu32;
typedef __attribute__((address_space(3))) unsigned int lu32;

static __device__ __forceinline__ ushort f2bf(float f) {
    union { __hip_bfloat16 h; ushort u; } cv;
    cv.h = __float2bfloat16(f);
    return cv.u;
}

// wp[ks][o][j][e] = bf16(W[o][kc]) with kc = ks*BK + (j ^ (o&7))*8 + e.
// Per-step LDS image PRE-swizzled so a linear global_load_lds lands such
// that byte (o*128 + oc*16)^((o&7)<<4) holds W[o][kc0 + oc*8 .. +8].
__global__ __launch_bounds__(256) void prepack_w(const float* __restrict__ w,
                                                 __hip_bfloat16* __restrict__ wp) {
    int idx = blockIdx.x * 256 + threadIdx.x;      // NSTEP*COUT*BK = 196608
    if (idx >= NSTEP * COUT * BK) return;
    int e  = idx & 7;
    int j  = (idx >> 3) & 7;
    int o  = (idx >> 6) & (COUT - 1);
    int ks = idx >> 14;
    int kc = ks * BK + ((j ^ (o & 7)) << 3) + e;
    int k  = kc >> 8;              // / CIN
    int c  = kc & (CIN - 1);
    wp[idx] = __float2bfloat16(w[(o * CIN + c) * KS + k]);
}

static __device__ __forceinline__ void issue_gather(const float* __restrict__ xr,
                                                    int i0, int i1, float g[16]) {
    #pragma unroll
    for (int i = 0; i < 8; ++i) {
        g[2 * i]     = xr[i0];
        g[2 * i + 1] = xr[i1];
        xr += TDIM;
    }
}

static __device__ __forceinline__ bf16x8 pack8(const float g[16], float w0, float w1) {
    bf16x8 r;
    #pragma unroll
    for (int i = 0; i < 8; ++i)
        r[i] = (short)f2bf(g[2 * i] * w0 + g[2 * i + 1] * w1);
    return r;
}

__global__ __launch_bounds__(512, 4) void deform_mfma(
    const float* __restrict__ x,              // (NB, CIN, TDIM)
    const float* __restrict__ off,            // (NB, 2*KS, TDIM, 1)
    const __hip_bfloat16* __restrict__ wp,    // swizzled pack, 384 KB
    const float* __restrict__ bias,           // (COUT)
    float* __restrict__ out)                  // (NB, COUT, TDIM)
{
    __shared__ ushort w_s[COUT * BK];   // 32 KB, swizzled image per step
    __shared__ ushort v_s[TT * BK];     // 16 KB, swizzled
    __shared__ int4   sP[KS][TT];       // {i0, i1, w0f, w1f} per (k, t)  6 KB

    const int tid = threadIdx.x;
    const int b   = blockIdx.y;
    const int tt0 = blockIdx.x * TT;

    // ---- Phase A: per-(k,t) gather indices & interp weights ----
    if (tid < KS * TT) {
        int k = tid >> 7, j = tid & (TT - 1);
        int t = tt0 + j;
        float dyr = off[((b * 2 * KS + 2 * k) * TDIM) + t];
        float dxr = off[((b * 2 * KS + 2 * k + 1) * TDIM) + t];
        float py  = (float)(t - PADV + k) + dyr - (float)(k - PADV);
        float i0f = floorf(py);
        float fr  = py - i0f;
        int i0 = (int)i0f, i1 = i0 + 1;
        float wx = fmaxf(0.0f, 1.0f - fabsf(dxr));
        float w0 = (1.0f - fr) * wx * ((i0 >= 0 && i0 < TDIM) ? 1.0f : 0.0f);
        float w1 = fr * wx * ((i1 >= 0 && i1 < TDIM) ? 1.0f : 0.0f);
        int4 p;
        p.x = min(max(i0, 0), TDIM - 1);
        p.y = min(max(i1, 0), TDIM - 1);
        p.z = __float_as_int(w0);
        p.w = __float_as_int(w1);
        sP[k][j] = p;
    }

    const int wid    = tid >> 6;
    const int lane   = tid & 63;
    const int o_base = (wid >> 1) * 64;
    const int t_base = (wid & 1) * 64;
    const int lr     = lane & 15;
    const int lg     = lane >> 4;

    const int coct0 = tid >> 7;          // 0..3
    const int t     = tid & (TT - 1);
    const int vrow  = t * (BK * 2);
    const int vswz  = (t & 7) << 4;
    const int voff0 = (vrow + coct0 * 16) ^ vswz;
    const int voff1 = (vrow + (coct0 + 4) * 16) ^ vswz;

    f32x4 acc[4][4];
    #pragma unroll
    for (int i = 0; i < 4; ++i)
        #pragma unroll
        for (int j = 0; j < 4; ++j) acc[i][j] = (f32x4)0.0f;

    const float* xb = x + (size_t)b * CIN * TDIM;

    __syncthreads();   // sP visible to all

    // ---- Prologue: gather+pack step 0 (exposed once) ----
    bf16x8 pk0, pk1;
    {
        int4 p = sP[0][t];
        float gA[16], gB[16];
        issue_gather(xb + (size_t)(coct0 * 8) * TDIM,        p.x, p.y, gA);
        issue_gather(xb + (size_t)(32 + coct0 * 8) * TDIM,   p.x, p.y, gB);
        float w0 = __int_as_float(p.z), w1 = __int_as_float(p.w);
        pk0 = pack8(gA, w0, w1);
        pk1 = pack8(gB, w0, w1);
    }

    #pragma unroll 1
    for (int ks = 0; ks < NSTEP; ++ks) {
        const int ksn = (ks + 1 < NSTEP) ? (ks + 1) : (NSTEP - 1);
        const int kcn = ksn * BK;
        const int kn  = kcn >> 8;
        const int c0n = kcn & (CIN - 1);

        // a: all waves finished reading LDS(ks-1)
        __builtin_amdgcn_s_barrier();
        __builtin_amdgcn_sched_barrier(0);

        // b: W-DMA(ks), oldest vmem ops of this step
        {
            const char* gbase = (const char*)wp + (size_t)ks * 32768 + wid * 4096 + lane * 16;
            char* lbase = (char*)w_s + wid * 4096;   // wave-uniform
            #pragma unroll
            for (int i = 0; i < 4; ++i)
                __builtin_amdgcn_global_load_lds((gu32*)(gbase + i * 1024),
                                                 (lu32*)(lbase + i * 1024), 16, 0, 0);
        }
        __builtin_amdgcn_sched_barrier(0);

        // c: commit V(ks) from registers packed last iteration
        *(bf16x8*)((char*)v_s + voff0) = pk0;
        *(bf16x8*)((char*)v_s + voff1) = pk1;
        __builtin_amdgcn_sched_barrier(0);

        // d: issue first-half gathers for ks+1 (16 loads, stay in flight)
        int4 pn = sP[kn][t];
        float gA[16];
        issue_gather(xb + (size_t)(c0n + coct0 * 8) * TDIM, pn.x, pn.y, gA);
        __builtin_amdgcn_sched_barrier(0);

        // e: drain W-DMA (4 oldest of 20 outstanding) + own LDS ops
        asm volatile("s_waitcnt vmcnt(16) lgkmcnt(0)" ::: "memory");

        // f: LDS(ks) fully valid across the block
        __builtin_amdgcn_s_barrier();
        __builtin_amdgcn_sched_barrier(0);

        // g: MFMA(ks) — 64(o) x 64(t), K=64 per wave
        #pragma unroll
        for (int kb = 0; kb < 2; ++kb) {
            const int kk = kb * 32 + lg * 8;
            bf16x8 bfr[4];
            #pragma unroll
            for (int nf = 0; nf < 4; ++nf) {
                int tc = t_base + nf * 16 + lr;
                int byte = (tc * (BK * 2) + kk * 2) ^ ((tc & 7) << 4);
                bfr[nf] = *(const bf16x8*)((const char*)v_s + byte);
            }
            #pragma unroll
            for (int mf = 0; mf < 4; ++mf) {
                int o  = o_base + mf * 16 + lr;
                int byte = (o * (BK * 2) + kk * 2) ^ ((o & 7) << 4);
                bf16x8 af = *(const bf16x8*)((const char*)w_s + byte);
                #pragma unroll
                for (int nf = 0; nf < 4; ++nf)
                    acc[mf][nf] = __builtin_amdgcn_mfma_f32_16x16x32_bf16(
                        af, bfr[nf], acc[mf][nf], 0, 0, 0);
            }
        }
        __builtin_amdgcn_sched_barrier(0);

        // h: second-half gathers for ks+1, then pack both halves -> pk regs
        {
            float gB[16];
            issue_gather(xb + (size_t)(c0n + 32 + coct0 * 8) * TDIM, pn.x, pn.y, gB);
            float w0 = __int_as_float(pn.z), w1 = __int_as_float(pn.w);
            pk0 = pack8(gA, w0, w1);
            pk1 = pack8(gB, w0, w1);
        }
    }

    // ---- Epilogue: D col = lane&15 (t), row = (lane>>4)*4 + reg (o) ----
    #pragma unroll
    for (int mf = 0; mf < 4; ++mf) {
        #pragma unroll
        for (int r = 0; r < 4; ++r) {
            int o = o_base + mf * 16 + lg * 4 + r;
            float bv = bias[o];
            float* orow = out + (size_t)(b * COUT + o) * TDIM + tt0 + t_base;
            #pragma unroll
            for (int nf = 0; nf < 4; ++nf)
                orow[nf * 16 + lr] = acc[mf][nf][r] + bv;
        }
    }
}

extern "C" void kernel_launch(void* const* d_in, const int* in_sizes, int n_in,
                              void* d_out, int out_size, void* d_ws, size_t ws_size,
                              hipStream_t stream) {
    const float* x    = (const float*)d_in[0];
    const float* off  = (const float*)d_in[1];
    const float* w    = (const float*)d_in[2];
    const float* bias = (const float*)d_in[3];
    float* out = (float*)d_out;
    __hip_bfloat16* wp = (__hip_bfloat16*)d_ws;   // 384 KB swizzled pack

    prepack_w<<<dim3((NSTEP * COUT * BK + 255) / 256), dim3(256), 0, stream>>>(w, wp);

    dim3 grid(TDIM / TT, NB);
    deform_mfma<<<grid, dim3(512), 0, stream>>>(x, off, wp, bias, out);
}

// Round 6
// 81.835 us; speedup vs baseline: 2.3515x; 2.3515x over previous
//
#include <hip/hip_runtime.h>
#include <hip/hip_bf16.h>

typedef __attribute__((ext_vector_type(8))) short bf16x8;
typedef __attribute__((ext_vector_type(4))) float f32x4;

constexpr int NB = 16, CIN = 256, COUT = 256, TDIM = 4096, KS = 3, PADV = 1;
constexpr int TT = 128;            // t per block
constexpr int BK = 64;             // K-step (64 channels of one tap)
constexpr int NSTEP = 12;          // 4 c-blocks x 3 taps

typedef __attribute__((address_space(1))) const unsigned int gu32;
typedef __attribute__((address_space(3))) unsigned int lu32;

static __device__ __forceinline__ ushort f2bf(float f) {
    union { __hip_bfloat16 h; ushort u; } cv;
    cv.h = __float2bfloat16(f);
    return cv.u;
}

// Step s = cb*3 + k covers channels [cb*64, cb*64+64) of tap k (c-major so
// consecutive steps reuse the same x rows). Per-step LDS image PRE-swizzled
// so a linear global_load_lds lands such that byte (o*128 + oc*16)^((o&7)<<4)
// holds W[o][tap k][c0 + oc*8 .. +8].
__global__ __launch_bounds__(256) void prepack_w(const float* __restrict__ w,
                                                 __hip_bfloat16* __restrict__ wp) {
    int idx = blockIdx.x * 256 + threadIdx.x;      // NSTEP*COUT*BK = 196608
    if (idx >= NSTEP * COUT * BK) return;
    int e  = idx & 7;
    int j  = (idx >> 3) & 7;
    int o  = (idx >> 6) & (COUT - 1);
    int s  = idx >> 14;                            // 0..11
    int k  = s % 3;
    int c  = (s / 3) * 64 + ((j ^ (o & 7)) << 3) + e;
    wp[idx] = __float2bfloat16(w[(o * CIN + c) * KS + k]);
}

__global__ __launch_bounds__(512, 4) void deform_mfma(
    const float* __restrict__ x,              // (NB, CIN, TDIM)
    const float* __restrict__ off,            // (NB, 2*KS, TDIM, 1)
    const __hip_bfloat16* __restrict__ wp,    // swizzled pack, 384 KB
    const float* __restrict__ bias,           // (COUT)
    float* __restrict__ out)                  // (NB, COUT, TDIM)
{
    __shared__ ushort w_s[COUT * BK];   // 32 KB, swizzled image per step
    __shared__ ushort v_s[TT * BK];     // 16 KB, swizzled
    __shared__ int4   sP[KS][TT];       // {i0, i1, w0f, w1f} per (k, t)  6 KB

    const int tid = threadIdx.x;

    // XCD-chunked bijective swizzle: XCD q (= bid%8) owns batches {2q, 2q+1}
    // -> per-XCD x working set 8 MB instead of 32 MB.
    const int bid  = blockIdx.x;           // 0..511
    const int q    = bid & 7;
    const int r    = bid >> 3;             // 0..63
    const int b    = 2 * q + (r >> 5);
    const int tt0  = (r & 31) * TT;

    // ---- Phase A: per-(k,t) gather indices & interp weights ----
    if (tid < KS * TT) {
        int k = tid >> 7, j = tid & (TT - 1);
        int t = tt0 + j;
        float dyr = off[((b * 2 * KS + 2 * k) * TDIM) + t];
        float dxr = off[((b * 2 * KS + 2 * k + 1) * TDIM) + t];
        float py  = (float)(t - PADV + k) + dyr - (float)(k - PADV);
        float i0f = floorf(py);
        float fr  = py - i0f;
        int i0 = (int)i0f, i1 = i0 + 1;
        float wx = fmaxf(0.0f, 1.0f - fabsf(dxr));
        float w0 = (1.0f - fr) * wx * ((i0 >= 0 && i0 < TDIM) ? 1.0f : 0.0f);
        float w1 = fr * wx * ((i1 >= 0 && i1 < TDIM) ? 1.0f : 0.0f);
        int4 p;
        p.x = min(max(i0, 0), TDIM - 1);
        p.y = min(max(i1, 0), TDIM - 1);
        p.z = __float_as_int(w0);
        p.w = __float_as_int(w1);
        sP[k][j] = p;
    }

    const int wid    = tid >> 6;
    const int lane   = tid & 63;
    const int o_base = (wid >> 1) * 64;
    const int t_base = (wid & 1) * 64;
    const int lr     = lane & 15;
    const int lg     = lane >> 4;

    f32x4 acc[4][4];
    #pragma unroll
    for (int i = 0; i < 4; ++i)
        #pragma unroll
        for (int j = 0; j < 4; ++j) acc[i][j] = (f32x4)0.0f;

    const float* xb = x + (size_t)b * CIN * TDIM;

    for (int cb = 0; cb < 4; ++cb) {
      for (int k = 0; k < 3; ++k) {
        const int s_idx = cb * 3 + k;
        const int c0    = cb * 64;
        __syncthreads();   // MFMA(prev) done -> LDS writable; sP visible (s=0)

        // ---- stage W: direct global->LDS DMA, pre-swizzled source ----
        {
            const char* gbase = (const char*)wp + (size_t)s_idx * 32768 + wid * 4096 + lane * 16;
            char* lbase = (char*)w_s + wid * 4096;   // wave-uniform
            #pragma unroll
            for (int i = 0; i < 4; ++i)
                __builtin_amdgcn_global_load_lds((gu32*)(gbase + i * 1024),
                                                 (lu32*)(lbase + i * 1024), 16, 0, 0);
        }

        // ---- stage V: ALL 32 gather loads first, then math ----
        {
            const int coct0 = tid >> 7;          // 0..3
            const int t     = tid & (TT - 1);
            int4 p = sP[k][t];
            const float* xr0 = xb + (size_t)(c0 + coct0 * 8) * TDIM;
            const float* xr1 = xr0 + (size_t)32 * TDIM;   // coct0+4
            float g0[16], g1[16];
            #pragma unroll
            for (int i = 0; i < 8; ++i) {
                g0[2 * i]     = xr0[p.x];
                g0[2 * i + 1] = xr0[p.y];
                xr0 += TDIM;
            }
            #pragma unroll
            for (int i = 0; i < 8; ++i) {
                g1[2 * i]     = xr1[p.x];
                g1[2 * i + 1] = xr1[p.y];
                xr1 += TDIM;
            }
            float w0 = __int_as_float(p.z), w1 = __int_as_float(p.w);
            bf16x8 pk0, pk1;
            #pragma unroll
            for (int i = 0; i < 8; ++i) {
                pk0[i] = (short)f2bf(g0[2 * i] * w0 + g0[2 * i + 1] * w1);
                pk1[i] = (short)f2bf(g1[2 * i] * w0 + g1[2 * i + 1] * w1);
            }
            int row = t * (BK * 2);
            int swz = (t & 7) << 4;
            *(bf16x8*)((char*)v_s + ((row + coct0 * 16) ^ swz))       = pk0;
            *(bf16x8*)((char*)v_s + ((row + (coct0 + 4) * 16) ^ swz)) = pk1;
        }

        __syncthreads();   // drains gathers + load_lds + ds_writes

        // ---- MFMA: wave computes 64(o) x 64(t), K=64 ----
        #pragma unroll
        for (int kb = 0; kb < 2; ++kb) {
            const int kk = kb * 32 + lg * 8;
            bf16x8 bfr[4];
            #pragma unroll
            for (int nf = 0; nf < 4; ++nf) {
                int tc = t_base + nf * 16 + lr;
                int byte = (tc * (BK * 2) + kk * 2) ^ ((tc & 7) << 4);
                bfr[nf] = *(const bf16x8*)((const char*)v_s + byte);
            }
            #pragma unroll
            for (int mf = 0; mf < 4; ++mf) {
                int o  = o_base + mf * 16 + lr;
                int byte = (o * (BK * 2) + kk * 2) ^ ((o & 7) << 4);
                bf16x8 af = *(const bf16x8*)((const char*)w_s + byte);
                #pragma unroll
                for (int nf = 0; nf < 4; ++nf)
                    acc[mf][nf] = __builtin_amdgcn_mfma_f32_16x16x32_bf16(
                        af, bfr[nf], acc[mf][nf], 0, 0, 0);
            }
        }
      }
    }

    // ---- Epilogue: D col = lane&15 (t), row = (lane>>4)*4 + reg (o) ----
    #pragma unroll
    for (int mf = 0; mf < 4; ++mf) {
        #pragma unroll
        for (int r2 = 0; r2 < 4; ++r2) {
            int o = o_base + mf * 16 + lg * 4 + r2;
            float bv = bias[o];
            float* orow = out + (size_t)(b * COUT + o) * TDIM + tt0 + t_base;
            #pragma unroll
            for (int nf = 0; nf < 4; ++nf)
                orow[nf * 16 + lr] = acc[mf][nf][r2] + bv;
        }
    }
}

extern "C" void kernel_launch(void* const* d_in, const int* in_sizes, int n_in,
                              void* d_out, int out_size, void* d_ws, size_t ws_size,
                              hipStream_t stream) {
    const float* x    = (const float*)d_in[0];
    const float* off  = (const float*)d_in[1];
    const float* w    = (const float*)d_in[2];
    const float* bias = (const float*)d_in[3];
    float* out = (float*)d_out;
    __hip_bfloat16* wp = (__hip_bfloat16*)d_ws;   // 384 KB swizzled pack

    prepack_w<<<dim3((NSTEP * COUT * BK + 255) / 256), dim3(256), 0, stream>>>(w, wp);

    dim3 grid(512);
    deform_mfma<<<grid, dim3(512), 0, stream>>>(x, off, wp, bias, out);
}